// Round 7
// baseline (344.601 us; speedup 1.0000x reference)
//
#include <hip/hip_runtime.h>

// ResidualVQ: Q=4, N_EMBED=1024, DIM=256, B=8, S=2048 (fp32).
// out = [quantized 8*2048*256][indices-as-float 4*8*2048][losses 4]
//
// R19: double clean TLP. R18 proved spill was not the critical path (WRITE
// 104->22MB, dur flat 283->279): the cost is per-wave serial latency (kc-loop
// B-loads from L2 + barrier drains) with only 2 waves/SIMD of cover. This
// round: 1024 threads = 16 waves (4/SIMD), each wave owns 64 codes (4
// col-tiles, acc[2][4]=32 regs) -> per-wave chains halve, TLP doubles, block
// B-reuse (R14's win) unchanged. Regs fit (1024,4)'s 128 cap with the
// R16-proven acc=32 live across the barrier.
// Row mappings: R13-verified x32 set (av tree, 1 slot/thread re-rank, STE
// d0=j32*8). Exactness: d~ kc-order unchanged; min/max regroupings exact;
// candidate set identical (order-free re-rank); fallback same distances+tie
// rule. Outputs bit-identical to R18.
#define QQ   4
#define NE   1024
#define DIMD 256
#define MM   16384
#define TM   32
#define NW   16     // waves per block (1024 threads)
#define CAP  32     // candidate slots per row

typedef short v8s __attribute__((ext_vector_type(8)));   // 8 x bf16
typedef float v4f __attribute__((ext_vector_type(4)));

// ws layout (float offsets):
//  cb16  [QQ][NE][DIMD] ushort @ 0        (524,288 floats)
//  bK    [QQ][NE]              @ 524,288  (4,096)
//  lossP double[QQ][64]        @ 528,384  (byte 2,113,536 %8==0; 512 floats)
//  done  uint                  @ 528,896

__device__ __forceinline__ unsigned short f2bf(float f) {  // RNE fp32->bf16
  unsigned u = __float_as_uint(f);
  return (unsigned short)((u + 0x7FFFu + ((u >> 16) & 1u)) >> 16);
}

// FROZEN numpy pairwise sumsq of 256 f32, over a 32-aligned group of 32 lanes
// (j = lane-in-group). Valid on j==0. Identical op tree/pairing as scalar.
__device__ __forceinline__ float np_sumsq_256_x32(const float* __restrict__ p,
                                                  int j) {
  const int bi = j >> 4, L = j & 15;
  const float* q = p + bi * 128 + L;
  float s0 = __fmul_rn(q[0], q[0]);
  float s1 = __fmul_rn(q[16], q[16]);
  float s2 = __fmul_rn(q[32], q[32]);
  float s3 = __fmul_rn(q[48], q[48]);
  float s4 = __fmul_rn(q[64], q[64]);
  float s5 = __fmul_rn(q[80], q[80]);
  float s6 = __fmul_rn(q[96], q[96]);
  float s7 = __fmul_rn(q[112], q[112]);
  float w = __fadd_rn(__fadd_rn(__fadd_rn(s0, s1), __fadd_rn(s2, s3)),
                      __fadd_rn(__fadd_rn(s4, s5), __fadd_rn(s6, s7)));
  float u  = __fadd_rn(w,  __shfl_down(w, 8, 64));   // valid L<8
  float t  = __fadd_rn(u,  __shfl_down(u, 4, 64));   // valid L<4
  float r2 = __fadd_rn(t,  __shfl_down(t, 2, 64));   // valid L<2
  float bb = __fadd_rn(r2, __shfl_down(r2, 1, 64));  // valid L==0 -> blk[bi]
  return __fadd_rn(bb, __shfl_down(bb, 16, 64));     // valid j==0
}

// frozen np distance, float4-load pipelined (IDENTICAL fma sequence/order)
__device__ __forceinline__ float np_dist_f4(const float* __restrict__ xp,
                                            const float* __restrict__ ep,
                                            float a, float b) {
  float m = 0.f;
  #pragma unroll 16
  for (int d4 = 0; d4 < DIMD / 4; ++d4) {
    const float4 xv = *(const float4*)(xp + d4 * 4);
    const float4 ev = *(const float4*)(ep + d4 * 4);
    m = fmaf(xv.x, ev.x, m);
    m = fmaf(xv.y, ev.y, m);
    m = fmaf(xv.z, ev.z, m);
    m = fmaf(xv.w, ev.w, m);
  }
  return __fadd_rn(__fsub_rn(a, __fmul_rn(2.0f, m)), b);
}

// fused prep: bf16 conversion of all codebooks + bK (frozen np sumsq) +
// zero lossP/done. 1024 blocks x 256 threads.
__global__ __launch_bounds__(256) void k_prep(const float* __restrict__ cb,
                                              unsigned short* __restrict__ cb16,
                                              float* __restrict__ bK,
                                              double* __restrict__ lossP,
                                              unsigned* __restrict__ done) {
  const int g = blockIdx.x * 256 + threadIdx.x;  // 0..262143
  {  // cb16: 4 elements per thread, exactly covers QQ*NE*DIMD
    const int i = g * 4;
    float4 f = *(const float4*)(cb + i);
    unsigned short t[4] = {f2bf(f.x), f2bf(f.y), f2bf(f.z), f2bf(f.w)};
    *(short4*)(cb16 + i) = *(short4*)t;
  }
  if (g < QQ * NE * 32) {  // bK: 32 lanes per row (frozen np tree)
    const int row = g >> 5, j = g & 31;
    float b = np_sumsq_256_x32(cb + (size_t)row * DIMD, j);
    if (j == 0) bK[row] = b;
  }
  if (g < QQ * 64) lossP[g] = 0.0;
  if (g == 0) *done = 0u;
}

// 1024 threads = 16 waves; block owns TM=32 rows through ALL 4 stages.
// Wave w covers codes [w*64,(w+1)*64): 4 col-tiles x 2 row-tiles per wave.
// launch_bounds(1024,4): <=128 regs/wave, 4 waves/SIMD (2x R18's TLP).
__global__ __launch_bounds__(1024, 4) void k_fused(
    const float* __restrict__ x,              // [MM][DIMD]
    const unsigned short* __restrict__ cb16a, // [QQ][NE][DIMD] bf16
    const float* __restrict__ cba,            // [QQ][NE][DIMD] fp32
    const float* __restrict__ bKa,            // [QQ][NE]
    double* __restrict__ lossP,               // [QQ][64]
    unsigned* __restrict__ doneCnt,           // grid done counter
    float* __restrict__ out_q,                // [MM][DIMD]
    float* __restrict__ idx_out,              // [QQ][MM] floats
    float* __restrict__ out_loss) {           // [QQ]
  __shared__ float residF[TM][DIMD + 4];       // fp32 residual, all 4 stages
  __shared__ unsigned short sX[TM][DIMD + 8];  // bf16 rows
  __shared__ float  sBK[NE];                   // bK staged per stage
  __shared__ float  av_s[TM];
  __shared__ float  candD[TM][NW];
  __shared__ float  thrS[TM];
  __shared__ int    cnt[TM];
  __shared__ int    candL[TM][CAP];
  __shared__ float  dcD[TM][CAP];
  __shared__ int    bcode[TM];
  __shared__ float  fwD[NW];
  __shared__ int    fwI[NW];
  __shared__ double lossW[NW];

  const int tid  = threadIdx.x;
  const int lane = tid & 63;
  const int wv   = tid >> 6;       // wave 0..15
  const int rowBase = blockIdx.x * TM;
  const int r32 = tid >> 5;        // row 0..31 (32 threads per row)
  const int j32 = tid & 31;        // lane in row-group
  const int d0  = j32 * 8;         // 8 floats per thread per row
  const int m16  = lane & 15;
  const int quad = lane >> 4;

  // x -> residF (exact fp32; stage-0 residual == x)
  {
    const float* xp = x + (size_t)(rowBase + r32) * DIMD + d0;
    *(float4*)&residF[r32][d0]     = *(const float4*)xp;
    *(float4*)&residF[r32][d0 + 4] = *(const float4*)(xp + 4);
  }
  __syncthreads();

  #pragma unroll 1
  for (int qi = 0; qi < QQ; ++qi) {
    const unsigned short* cb16 = cb16a + (size_t)qi * NE * DIMD;
    const float* cb = cba + (size_t)qi * NE * DIMD;
    const float* bK = bKa + (size_t)qi * NE;

    // av (FROZEN, 32-lane tree, from LDS) + cnt reset + bK->LDS + bf16 staging
    {
      float av = np_sumsq_256_x32(&residF[r32][0], j32);
      if (j32 == 0) av_s[r32] = av;
    }
    if (tid < TM) cnt[tid] = 0;
    if (tid < NE) sBK[tid] = bK[tid];
    {
      const float* rp = &residF[r32][d0];
      const float4 f0 = *(const float4*)rp;
      const float4 f1 = *(const float4*)(rp + 4);
      unsigned short t[8] = {f2bf(f0.x), f2bf(f0.y), f2bf(f0.z), f2bf(f0.w),
                             f2bf(f1.x), f2bf(f1.y), f2bf(f1.z), f2bf(f1.w)};
      *(v8s*)&sX[r32][d0] = *(v8s*)t;
    }
    __syncthreads();

    // per-wave bmax over sBK (fp32 fmax == old atomicMax value bit-exactly;
    // bK > 0 always). 16 LDS reads + shfl reduce per wave.
    float bmx;
    {
      float bm = sBK[lane];
      #pragma unroll
      for (int t = 1; t < 16; ++t) bm = fmaxf(bm, sBK[lane + t * 64]);
      #pragma unroll
      for (int off = 32; off; off >>= 1) bm = fmaxf(bm, __shfl_xor(bm, off, 64));
      bmx = bm;
    }

    // MFMA: M~[row][code], 2 row-tiles x 4 col-tiles per wave; per kc all 4
    // B-fragments batched (4 dwordx4 in flight), 8 MFMAs. acc kc-order
    // identical to R18 -> d~ bit-identical.
    v4f acc[2][4];
    #pragma unroll
    for (int mt = 0; mt < 2; ++mt)
      #pragma unroll
      for (int ct = 0; ct < 4; ++ct) acc[mt][ct] = (v4f)(0.f);
    const unsigned short* bptr =
        cb16 + ((size_t)(wv * 64 + m16)) * DIMD + quad * 8;
    #pragma unroll
    for (int kc = 0; kc < 8; ++kc) {
      v8s bfr[4];
      #pragma unroll
      for (int ct = 0; ct < 4; ++ct)
        bfr[ct] = *(const v8s*)(bptr + (size_t)ct * 16 * DIMD + kc * 32);
      v8s a0 = *(const v8s*)&sX[m16][kc * 32 + quad * 8];
      v8s a1 = *(const v8s*)&sX[16 + m16][kc * 32 + quad * 8];
      #pragma unroll
      for (int ct = 0; ct < 4; ++ct) {
        acc[0][ct] = __builtin_amdgcn_mfma_f32_16x16x32_bf16(a0, bfr[ct], acc[0][ct], 0, 0, 0);
        acc[1][ct] = __builtin_amdgcn_mfma_f32_16x16x32_bf16(a1, bfr[ct], acc[1][ct], 0, 0, 0);
      }
    }

    // approx dist in-place: d~ = a - 2*M~ + b  (D: row=mt*16+quad*4+v, col=m16)
    float av8[2][4];
    #pragma unroll
    for (int mt = 0; mt < 2; ++mt)
      #pragma unroll
      for (int v = 0; v < 4; ++v) av8[mt][v] = av_s[mt * 16 + quad * 4 + v];
    #pragma unroll
    for (int ct = 0; ct < 4; ++ct) {
      const float bv = sBK[wv * 64 + ct * 16 + m16];
      #pragma unroll
      for (int mt = 0; mt < 2; ++mt)
        #pragma unroll
        for (int v = 0; v < 4; ++v)
          acc[mt][ct][v] = av8[mt][v] - 2.0f * acc[mt][ct][v] + bv;
    }

    // per-row min: over ct, then across the 16 lanes of each quad
    #pragma unroll
    for (int mt = 0; mt < 2; ++mt) {
      float vmin[4];
      #pragma unroll
      for (int v = 0; v < 4; ++v) {
        vmin[v] = acc[mt][0][v];
        #pragma unroll
        for (int ct = 1; ct < 4; ++ct) vmin[v] = fminf(vmin[v], acc[mt][ct][v]);
        #pragma unroll
        for (int off = 1; off < 16; off <<= 1)
          vmin[v] = fminf(vmin[v], __shfl_xor(vmin[v], off, 64));
      }
      if (m16 == 0) {
        #pragma unroll
        for (int v = 0; v < 4; ++v) candD[mt * 16 + quad * 4 + v][wv] = vmin[v];
      }
    }
    __syncthreads();
    if (tid < TM) {
      float bd = candD[tid][0];
      #pragma unroll
      for (int w = 1; w < NW; ++w) bd = fminf(bd, candD[tid][w]);
      // certified margin: 2*2^-8*sqrt(a*bmax) needed; 2^-5*sqrt(.)+0.1 = 8x slack
      thrS[tid] = bd + 0.03125f * sqrtf(av_s[tid] * bmx) + 0.1f;
    }
    __syncthreads();

    // gather candidates (acc=32 regs live across the barrier; R16-proven size)
    #pragma unroll
    for (int ct = 0; ct < 4; ++ct) {
      const int code = wv * 64 + ct * 16 + m16;
      #pragma unroll
      for (int mt = 0; mt < 2; ++mt) {
        #pragma unroll
        for (int v = 0; v < 4; ++v) {
          const int row = mt * 16 + quad * 4 + v;
          if (acc[mt][ct][v] <= thrS[row]) {
            int pos = atomicAdd(&cnt[row], 1);
            if (pos < CAP) candL[row][pos] = code;
          }
        }
      }
    }
    __syncthreads();

    // exact (frozen) distance per candidate: one thread per (row, slot)
    // (R13 mapping; x-row from LDS: identical fp32 values, identical fma order)
    {
      const int n = (cnt[r32] <= CAP) ? cnt[r32] : 0;  // overflow -> fallback
      if (j32 < n) {
        const int code = candL[r32][j32];
        dcD[r32][j32] = np_dist_f4(&residF[r32][0], cb + (size_t)code * DIMD,
                                   av_s[r32], sBK[code]);
      }
    }
    __syncthreads();

    // cooperative fallback for overflow rows (rare): 1 code/thread, exact,
    // same distance set + tie rule (strict <, lower index) as before
    for (int r = 0; r < TM; ++r) {
      if (cnt[r] > CAP) {
        const float* xp = &residF[r][0];
        const float a = av_s[r];
        float d1 = np_dist_f4(xp, cb + (size_t)tid * DIMD, a, sBK[tid]);
        int i1 = tid;
        #pragma unroll
        for (int off = 32; off; off >>= 1) {
          float vd = __shfl_xor(d1, off, 64);
          int vi = __shfl_xor(i1, off, 64);
          if (vd < d1 || (vd == d1 && vi < i1)) { d1 = vd; i1 = vi; }
        }
        if (lane == 0) { fwD[wv] = d1; fwI[wv] = i1; }
        __syncthreads();
        if (tid == 0) {
          float bd = fwD[0];
          int bi = fwI[0];
          #pragma unroll
          for (int w = 1; w < NW; ++w) {
            if (fwD[w] < bd || (fwD[w] == bd && fwI[w] < bi)) {
              bd = fwD[w]; bi = fwI[w];
            }
          }
          bcode[r] = bi;
        }
        __syncthreads();
      }
    }

    if (tid < TM) {
      if (cnt[tid] <= CAP) {
        float bd = 3.4e38f;
        int bi = 0x7fffffff;
        for (int ci = 0; ci < cnt[tid]; ++ci) {
          float d = dcD[tid][ci];
          int code = candL[tid][ci];
          if (d < bd || (d == bd && code < bi)) { bd = d; bi = code; }
        }
        bcode[tid] = bi;
      }
      idx_out[(size_t)qi * MM + rowBase + tid] = (float)bcode[tid];
    }
    __syncthreads();

    // STE update — FROZEN: t=fl(q-r); u=fl(r+t); r'=fl(r-u)  (in-LDS)
    const int codeB = bcode[r32];
    double lsum = 0.0;
    #pragma unroll
    for (int h = 0; h < 2; ++h) {
      const int d = d0 + h * 4;
      const float4 ev = *(const float4*)(cb + (size_t)codeB * DIMD + d);
      const float4 rv = *(const float4*)&residF[r32][d];
      float t0 = __fsub_rn(ev.x, rv.x), u0 = __fadd_rn(rv.x, t0);
      float t1 = __fsub_rn(ev.y, rv.y), u1 = __fadd_rn(rv.y, t1);
      float t2 = __fsub_rn(ev.z, rv.z), u2 = __fadd_rn(rv.z, t2);
      float t3 = __fsub_rn(ev.w, rv.w), u3 = __fadd_rn(rv.w, t3);
      *(float4*)&residF[r32][d] =
          make_float4(__fsub_rn(rv.x, u0), __fsub_rn(rv.y, u1),
                      __fsub_rn(rv.z, u2), __fsub_rn(rv.w, u3));
      lsum += (double)__fmul_rn(t0, t0) + (double)__fmul_rn(t1, t1) +
              (double)__fmul_rn(t2, t2) + (double)__fmul_rn(t3, t3);
    }
    #pragma unroll
    for (int off = 32; off; off >>= 1) lsum += __shfl_xor(lsum, off, 64);
    if (lane == 0) lossW[wv] = lsum;
    __syncthreads();   // also orders residF writes before next stage's reads
    if (tid == 0) {
      double s = 0.0;
      #pragma unroll
      for (int w = 0; w < NW; ++w) s += lossW[w];
      atomicAdd(lossP + (size_t)qi * 64 + (blockIdx.x & 63), s);
    }
  }

  // epilogue: out_q = fl(x - resid_final)
  {
    const float* xp = x + (size_t)(rowBase + r32) * DIMD + d0;
    float* op = out_q + (size_t)(rowBase + r32) * DIMD + d0;
    const float4 a0 = *(const float4*)xp;
    const float4 a1 = *(const float4*)(xp + 4);
    const float4 b0 = *(const float4*)&residF[r32][d0];
    const float4 b1 = *(const float4*)&residF[r32][d0 + 4];
    *(float4*)op = make_float4(__fsub_rn(a0.x, b0.x), __fsub_rn(a0.y, b0.y),
                               __fsub_rn(a0.z, b0.z), __fsub_rn(a0.w, b0.w));
    *(float4*)(op + 4) = make_float4(__fsub_rn(a1.x, b1.x), __fsub_rn(a1.y, b1.y),
                                     __fsub_rn(a1.z, b1.z), __fsub_rn(a1.w, b1.w));
  }

  // folded k_loss: last block to finish sums lossP (device-scope atomics
  // both sides; __threadfence orders this block's lossP adds before the
  // done increment).
  __syncthreads();
  if (tid == 0) {
    __threadfence();
    unsigned old = atomicAdd(doneCnt, 1u);
    cnt[0] = (old == (unsigned)(gridDim.x - 1)) ? 1 : 0;
  }
  __syncthreads();
  if (cnt[0] && tid < 64) {
    const int qi2 = tid >> 4;
    double s = 0.0;
    #pragma unroll
    for (int i = 0; i < 4; ++i)
      s += atomicAdd(lossP + (size_t)qi2 * 64 + (tid & 15) * 4 + i, 0.0);
    #pragma unroll
    for (int off = 8; off; off >>= 1) s += __shfl_down(s, off, 16);
    if ((tid & 15) == 0)
      out_loss[qi2] = (float)(s * (1.0 / (double)((size_t)MM * DIMD)));
  }
}

extern "C" void kernel_launch(void* const* d_in, const int* in_sizes, int n_in,
                              void* d_out, int out_size, void* d_ws, size_t ws_size,
                              hipStream_t stream) {
  const float* x = (const float*)d_in[0];        // [8,2048,256]
  const float* cb = (const float*)d_in[1];       // [4,1024,256]
  float* ws = (float*)d_ws;
  unsigned short* cb16 = (unsigned short*)ws;    // 1,048,576 ushort
  float* bK = ws + 524288;
  double* lossP = (double*)(ws + 528384);        // [QQ][64], byte off %8==0
  unsigned* done = (unsigned*)(ws + 528896);

  float* out = (float*)d_out;
  float* out_idx = out + (size_t)MM * DIMD;      // 4,194,304
  float* out_loss = out_idx + (size_t)QQ * MM;   // +65,536

  k_prep<<<dim3(1024), dim3(256), 0, stream>>>(cb, cb16, bK, lossP, done);
  k_fused<<<dim3(MM / TM), dim3(1024), 0, stream>>>(x, cb16, cb, bK, lossP,
                                                    done, out, out_idx, out_loss);
}

// Round 8
// 331.714 us; speedup vs baseline: 1.0389x; 1.0389x over previous
//
#include <hip/hip_runtime.h>

// ResidualVQ: Q=4, N_EMBED=1024, DIM=256, B=8, S=2048 (fp32).
// out = [quantized 8*2048*256][indices-as-float 4*8*2048][losses 4]
//
// R20: ONE block round. The R13-R19 matrix showed per-stage time ~=
// (per-block phase-chain cost) x (sequential rounds), insensitive to spill/
// occupancy/batch width; block count is the only lever that moved it
// (1024 blk ~100us/stage -> 512 blk ~70us/stage). TM=64: 256 blocks = 1
// block/CU = 1 round, and 4 MFMAs per B-fragment load (2x R14's B-reuse).
// 124KB dynamic LDS (gfx950: 160KB/CU) via hipFuncSetAttribute.
// launch_bounds(512,2): 256 regs/wave; acc[4][8]=128 + bfr[8]=32 fit clean.
// Frozen semantics: av tree re-split over 8 lanes/row (operand-pairing
// identical -> bit-exact); d~ kc-order, candidate predicate/tie rules,
// np_dist, STE all verbatim from R18. idx/resid bit-identical.
#define QQ   4
#define NE   1024
#define DIMD 256
#define MM   16384
#define TM   64
#define NW   8      // waves per block (512 threads)
#define CAP  32     // candidate slots per row

typedef short v8s __attribute__((ext_vector_type(8)));   // 8 x bf16
typedef float v4f __attribute__((ext_vector_type(4)));

// ws layout (float offsets):
//  cb16  [QQ][NE][DIMD] ushort @ 0        (524,288 floats)
//  bK    [QQ][NE]              @ 524,288  (4,096)
//  lossP double[QQ][64]        @ 528,384  (byte 2,113,536 %8==0; 512 floats)
//  done  uint                  @ 528,896

struct SLds {
  double lossW[NW];                  // 8-byte aligned first
  float  residF[TM][DIMD + 4];       // fp32 residual, all 4 stages (66,560B)
  unsigned short sX[TM][DIMD + 8];   // bf16 rows (33,792B)
  float  sBK[NE];                    // bK staged per stage (4,096B)
  float  av_s[TM];
  float  candD[TM][NW];
  float  thrS[TM];
  int    cnt[TM];
  int    candL[TM][CAP];             // 8,192B
  float  dcD[TM][CAP];               // 8,192B
  int    bcode[TM];
  float  fwD[NW];
  int    fwI[NW];
};

__device__ __forceinline__ unsigned short f2bf(float f) {  // RNE fp32->bf16
  unsigned u = __float_as_uint(f);
  return (unsigned short)((u + 0x7FFFu + ((u >> 16) & 1u)) >> 16);
}

// FROZEN numpy pairwise sumsq of 256 f32, over a 32-aligned group of 32 lanes
// (j = lane-in-group). Valid on j==0. Identical op tree/pairing as scalar.
__device__ __forceinline__ float np_sumsq_256_x32(const float* __restrict__ p,
                                                  int j) {
  const int bi = j >> 4, L = j & 15;
  const float* q = p + bi * 128 + L;
  float s0 = __fmul_rn(q[0], q[0]);
  float s1 = __fmul_rn(q[16], q[16]);
  float s2 = __fmul_rn(q[32], q[32]);
  float s3 = __fmul_rn(q[48], q[48]);
  float s4 = __fmul_rn(q[64], q[64]);
  float s5 = __fmul_rn(q[80], q[80]);
  float s6 = __fmul_rn(q[96], q[96]);
  float s7 = __fmul_rn(q[112], q[112]);
  float w = __fadd_rn(__fadd_rn(__fadd_rn(s0, s1), __fadd_rn(s2, s3)),
                      __fadd_rn(__fadd_rn(s4, s5), __fadd_rn(s6, s7)));
  float u  = __fadd_rn(w,  __shfl_down(w, 8, 64));   // valid L<8
  float t  = __fadd_rn(u,  __shfl_down(u, 4, 64));   // valid L<4
  float r2 = __fadd_rn(t,  __shfl_down(t, 2, 64));   // valid L<2
  float bb = __fadd_rn(r2, __shfl_down(r2, 1, 64));  // valid L==0 -> blk[bi]
  return __fadd_rn(bb, __shfl_down(bb, 16, 64));     // valid j==0
}

// Frozen tree over 8 lanes (j = 0..7 in an 8-aligned group). Lane j computes
// w[j] and w[j+8] in-register, so u[L]=w[L]+w[L+8] has the EXACT scalar
// operands; t/r2/blk via shfl as in the scalar pairing. Valid on j==0.
__device__ __forceinline__ float np_sumsq_256_x8(const float* __restrict__ p,
                                                 int j) {
  float blk[2];
  #pragma unroll
  for (int bi = 0; bi < 2; ++bi) {
    const float* base = p + bi * 128;
    float wpair[2];
    #pragma unroll
    for (int h = 0; h < 2; ++h) {          // L = j and j+8
      const float* q = base + j + h * 8;
      float s0 = __fmul_rn(q[0], q[0]);
      float s1 = __fmul_rn(q[16], q[16]);
      float s2 = __fmul_rn(q[32], q[32]);
      float s3 = __fmul_rn(q[48], q[48]);
      float s4 = __fmul_rn(q[64], q[64]);
      float s5 = __fmul_rn(q[80], q[80]);
      float s6 = __fmul_rn(q[96], q[96]);
      float s7 = __fmul_rn(q[112], q[112]);
      wpair[h] = __fadd_rn(__fadd_rn(__fadd_rn(s0, s1), __fadd_rn(s2, s3)),
                           __fadd_rn(__fadd_rn(s4, s5), __fadd_rn(s6, s7)));
    }
    float u  = __fadd_rn(wpair[0], wpair[1]);        // u[L]=w[L]+w[L+8], L=j
    float t  = __fadd_rn(u,  __shfl_down(u, 4, 64)); // valid j<4
    float r2 = __fadd_rn(t,  __shfl_down(t, 2, 64)); // valid j<2
    blk[bi]  = __fadd_rn(r2, __shfl_down(r2, 1, 64));// valid j==0
  }
  return __fadd_rn(blk[0], blk[1]);                  // valid j==0
}

// frozen np distance, float4-load pipelined (IDENTICAL fma sequence/order)
__device__ __forceinline__ float np_dist_f4(const float* __restrict__ xp,
                                            const float* __restrict__ ep,
                                            float a, float b) {
  float m = 0.f;
  #pragma unroll 16
  for (int d4 = 0; d4 < DIMD / 4; ++d4) {
    const float4 xv = *(const float4*)(xp + d4 * 4);
    const float4 ev = *(const float4*)(ep + d4 * 4);
    m = fmaf(xv.x, ev.x, m);
    m = fmaf(xv.y, ev.y, m);
    m = fmaf(xv.z, ev.z, m);
    m = fmaf(xv.w, ev.w, m);
  }
  return __fadd_rn(__fsub_rn(a, __fmul_rn(2.0f, m)), b);
}

// fused prep: bf16 conversion of all codebooks + bK (frozen np sumsq) +
// zero lossP/done. 1024 blocks x 256 threads.
__global__ __launch_bounds__(256) void k_prep(const float* __restrict__ cb,
                                              unsigned short* __restrict__ cb16,
                                              float* __restrict__ bK,
                                              double* __restrict__ lossP,
                                              unsigned* __restrict__ done) {
  const int g = blockIdx.x * 256 + threadIdx.x;  // 0..262143
  {  // cb16: 4 elements per thread, exactly covers QQ*NE*DIMD
    const int i = g * 4;
    float4 f = *(const float4*)(cb + i);
    unsigned short t[4] = {f2bf(f.x), f2bf(f.y), f2bf(f.z), f2bf(f.w)};
    *(short4*)(cb16 + i) = *(short4*)t;
  }
  if (g < QQ * NE * 32) {  // bK: 32 lanes per row (frozen np tree)
    const int row = g >> 5, j = g & 31;
    float b = np_sumsq_256_x32(cb + (size_t)row * DIMD, j);
    if (j == 0) bK[row] = b;
  }
  if (g < QQ * 64) lossP[g] = 0.0;
  if (g == 0) *done = 0u;
}

// 512 threads = 8 waves; block owns TM=64 rows through ALL 4 stages; 256
// blocks = 1/CU = ONE round. Wave w covers codes [w*128,(w+1)*128): 8
// col-tiles x 4 row-tiles (M_rep=4 -> 4 MFMAs per B-fragment load).
__global__ __launch_bounds__(512, 2) void k_fused(
    const float* __restrict__ x,              // [MM][DIMD]
    const unsigned short* __restrict__ cb16a, // [QQ][NE][DIMD] bf16
    const float* __restrict__ cba,            // [QQ][NE][DIMD] fp32
    const float* __restrict__ bKa,            // [QQ][NE]
    double* __restrict__ lossP,               // [QQ][64]
    unsigned* __restrict__ doneCnt,           // grid done counter
    float* __restrict__ out_q,                // [MM][DIMD]
    float* __restrict__ idx_out,              // [QQ][MM] floats
    float* __restrict__ out_loss) {           // [QQ]
  extern __shared__ char smem_raw[];
  SLds& S = *reinterpret_cast<SLds*>(smem_raw);

  const int tid  = threadIdx.x;
  const int lane = tid & 63;
  const int wv   = tid >> 6;       // wave 0..7
  const int rowBase = blockIdx.x * TM;
  const int r8  = tid >> 3;        // row 0..63 (8 threads per row)
  const int j8  = tid & 7;         // lane in row-group
  const int c0  = j8 * 32;         // 32 floats per thread per row
  const int m16  = lane & 15;
  const int quad = lane >> 4;

  // x -> residF (exact fp32; stage-0 residual == x)
  {
    const float* xp = x + (size_t)(rowBase + r8) * DIMD + c0;
    #pragma unroll
    for (int h = 0; h < 8; ++h)
      *(float4*)&S.residF[r8][c0 + h * 4] = *(const float4*)(xp + h * 4);
  }
  __syncthreads();

  #pragma unroll 1
  for (int qi = 0; qi < QQ; ++qi) {
    const unsigned short* cb16 = cb16a + (size_t)qi * NE * DIMD;
    const float* cb = cba + (size_t)qi * NE * DIMD;
    const float* bK = bKa + (size_t)qi * NE;

    // av (FROZEN x8 tree, from LDS) + cnt reset + bK->LDS + bf16 staging
    {
      float av = np_sumsq_256_x8(&S.residF[r8][0], j8);
      if (j8 == 0) S.av_s[r8] = av;
    }
    if (tid < TM) S.cnt[tid] = 0;
    S.sBK[tid] = bK[tid];
    S.sBK[tid + 512] = bK[tid + 512];
    {
      #pragma unroll
      for (int h = 0; h < 4; ++h) {
        const float* rp = &S.residF[r8][c0 + h * 8];
        const float4 f0 = *(const float4*)rp;
        const float4 f1 = *(const float4*)(rp + 4);
        unsigned short t[8] = {f2bf(f0.x), f2bf(f0.y), f2bf(f0.z), f2bf(f0.w),
                               f2bf(f1.x), f2bf(f1.y), f2bf(f1.z), f2bf(f1.w)};
        *(v8s*)&S.sX[r8][c0 + h * 8] = *(v8s*)t;
      }
    }
    __syncthreads();

    // per-wave bmax over sBK (fp32 fmax == old atomicMax value bit-exactly)
    float bmx;
    {
      float bm = S.sBK[lane];
      #pragma unroll
      for (int t = 1; t < 16; ++t) bm = fmaxf(bm, S.sBK[lane + t * 64]);
      #pragma unroll
      for (int off = 32; off; off >>= 1) bm = fmaxf(bm, __shfl_xor(bm, off, 64));
      bmx = bm;
    }

    // MFMA: M~[row][code], 4 row-tiles x 8 col-tiles per wave; per kc all 8
    // B-fragments batched (8 dwordx4 in flight), 32 MFMAs (4 per B-load).
    v4f acc[4][8];
    #pragma unroll
    for (int mt = 0; mt < 4; ++mt)
      #pragma unroll
      for (int ct = 0; ct < 8; ++ct) acc[mt][ct] = (v4f)(0.f);
    const unsigned short* bptr =
        cb16 + ((size_t)(wv * 128 + m16)) * DIMD + quad * 8;
    #pragma unroll
    for (int kc = 0; kc < 8; ++kc) {
      v8s bfr[8];
      #pragma unroll
      for (int ct = 0; ct < 8; ++ct)
        bfr[ct] = *(const v8s*)(bptr + (size_t)ct * 16 * DIMD + kc * 32);
      v8s afr[4];
      #pragma unroll
      for (int mt = 0; mt < 4; ++mt)
        afr[mt] = *(const v8s*)&S.sX[mt * 16 + m16][kc * 32 + quad * 8];
      #pragma unroll
      for (int ct = 0; ct < 8; ++ct) {
        #pragma unroll
        for (int mt = 0; mt < 4; ++mt)
          acc[mt][ct] = __builtin_amdgcn_mfma_f32_16x16x32_bf16(
              afr[mt], bfr[ct], acc[mt][ct], 0, 0, 0);
      }
    }

    // approx dist in-place: d~ = a - 2*M~ + b  (D: row=mt*16+quad*4+v, col=m16)
    float av16[4][4];
    #pragma unroll
    for (int mt = 0; mt < 4; ++mt)
      #pragma unroll
      for (int v = 0; v < 4; ++v) av16[mt][v] = S.av_s[mt * 16 + quad * 4 + v];
    #pragma unroll
    for (int ct = 0; ct < 8; ++ct) {
      const float bv = S.sBK[wv * 128 + ct * 16 + m16];
      #pragma unroll
      for (int mt = 0; mt < 4; ++mt)
        #pragma unroll
        for (int v = 0; v < 4; ++v)
          acc[mt][ct][v] = av16[mt][v] - 2.0f * acc[mt][ct][v] + bv;
    }

    // per-row min: over ct, then across the 16 lanes of each quad
    #pragma unroll
    for (int mt = 0; mt < 4; ++mt) {
      float vmin[4];
      #pragma unroll
      for (int v = 0; v < 4; ++v) {
        vmin[v] = acc[mt][0][v];
        #pragma unroll
        for (int ct = 1; ct < 8; ++ct) vmin[v] = fminf(vmin[v], acc[mt][ct][v]);
        #pragma unroll
        for (int off = 1; off < 16; off <<= 1)
          vmin[v] = fminf(vmin[v], __shfl_xor(vmin[v], off, 64));
      }
      if (m16 == 0) {
        #pragma unroll
        for (int v = 0; v < 4; ++v)
          S.candD[mt * 16 + quad * 4 + v][wv] = vmin[v];
      }
    }
    __syncthreads();
    if (tid < TM) {
      float bd = S.candD[tid][0];
      #pragma unroll
      for (int w = 1; w < NW; ++w) bd = fminf(bd, S.candD[tid][w]);
      // certified margin: 2*2^-8*sqrt(a*bmax) needed; 2^-5*sqrt(.)+0.1 = 8x slack
      S.thrS[tid] = bd + 0.03125f * sqrtf(S.av_s[tid] * bmx) + 0.1f;
    }
    __syncthreads();

    // gather candidates (acc live across the barrier; 256-reg budget holds it)
    #pragma unroll
    for (int ct = 0; ct < 8; ++ct) {
      const int code = wv * 128 + ct * 16 + m16;
      #pragma unroll
      for (int mt = 0; mt < 4; ++mt) {
        #pragma unroll
        for (int v = 0; v < 4; ++v) {
          const int row = mt * 16 + quad * 4 + v;
          if (acc[mt][ct][v] <= S.thrS[row]) {
            int pos = atomicAdd(&S.cnt[row], 1);
            if (pos < CAP) S.candL[row][pos] = code;
          }
        }
      }
    }
    __syncthreads();

    // exact (frozen) distance per candidate: thread (row, j8) covers slots
    // j8, j8+8, j8+16, j8+24 (x-row from LDS: same fp32 values, same fma order)
    {
      const int n = (S.cnt[r8] <= CAP) ? S.cnt[r8] : 0;  // overflow -> fallback
      #pragma unroll
      for (int s = 0; s < 4; ++s) {
        const int ci = j8 + s * 8;
        if (ci < n) {
          const int code = S.candL[r8][ci];
          S.dcD[r8][ci] = np_dist_f4(&S.residF[r8][0],
                                     cb + (size_t)code * DIMD,
                                     S.av_s[r8], S.sBK[code]);
        }
      }
    }
    __syncthreads();

    // cooperative fallback for overflow rows (rare): 2 codes/thread, exact
    for (int r = 0; r < TM; ++r) {
      if (S.cnt[r] > CAP) {
        const float* xp = &S.residF[r][0];
        const float a = S.av_s[r];
        float d1 = np_dist_f4(xp, cb + (size_t)tid * DIMD, a, S.sBK[tid]);
        float d2 = np_dist_f4(xp, cb + (size_t)(tid + 512) * DIMD, a, S.sBK[tid + 512]);
        int i1 = tid;
        if (d2 < d1) { d1 = d2; i1 = tid + 512; }  // strict <: lower idx on tie
        #pragma unroll
        for (int off = 32; off; off >>= 1) {
          float vd = __shfl_xor(d1, off, 64);
          int vi = __shfl_xor(i1, off, 64);
          if (vd < d1 || (vd == d1 && vi < i1)) { d1 = vd; i1 = vi; }
        }
        if (lane == 0) { S.fwD[wv] = d1; S.fwI[wv] = i1; }
        __syncthreads();
        if (tid == 0) {
          float bd = S.fwD[0];
          int bi = S.fwI[0];
          #pragma unroll
          for (int w = 1; w < NW; ++w) {
            if (S.fwD[w] < bd || (S.fwD[w] == bd && S.fwI[w] < bi)) {
              bd = S.fwD[w]; bi = S.fwI[w];
            }
          }
          S.bcode[r] = bi;
        }
        __syncthreads();
      }
    }

    if (tid < TM) {
      if (S.cnt[tid] <= CAP) {
        float bd = 3.4e38f;
        int bi = 0x7fffffff;
        for (int ci = 0; ci < S.cnt[tid]; ++ci) {
          float d = S.dcD[tid][ci];
          int code = S.candL[tid][ci];
          if (d < bd || (d == bd && code < bi)) { bd = d; bi = code; }
        }
        S.bcode[tid] = bi;
      }
      idx_out[(size_t)qi * MM + rowBase + tid] = (float)S.bcode[tid];
    }
    __syncthreads();

    // STE update — FROZEN: t=fl(q-r); u=fl(r+t); r'=fl(r-u)  (in-LDS)
    const int codeB = S.bcode[r8];
    double lsum = 0.0;
    #pragma unroll
    for (int h = 0; h < 8; ++h) {
      const int d = c0 + h * 4;
      const float4 ev = *(const float4*)(cb + (size_t)codeB * DIMD + d);
      const float4 rv = *(const float4*)&S.residF[r8][d];
      float t0 = __fsub_rn(ev.x, rv.x), u0 = __fadd_rn(rv.x, t0);
      float t1 = __fsub_rn(ev.y, rv.y), u1 = __fadd_rn(rv.y, t1);
      float t2 = __fsub_rn(ev.z, rv.z), u2 = __fadd_rn(rv.z, t2);
      float t3 = __fsub_rn(ev.w, rv.w), u3 = __fadd_rn(rv.w, t3);
      *(float4*)&S.residF[r8][d] =
          make_float4(__fsub_rn(rv.x, u0), __fsub_rn(rv.y, u1),
                      __fsub_rn(rv.z, u2), __fsub_rn(rv.w, u3));
      lsum += (double)__fmul_rn(t0, t0) + (double)__fmul_rn(t1, t1) +
              (double)__fmul_rn(t2, t2) + (double)__fmul_rn(t3, t3);
    }
    #pragma unroll
    for (int off = 32; off; off >>= 1) lsum += __shfl_xor(lsum, off, 64);
    if (lane == 0) S.lossW[wv] = lsum;
    __syncthreads();   // also orders residF writes before next stage's reads
    if (tid == 0) {
      double s = 0.0;
      #pragma unroll
      for (int w = 0; w < NW; ++w) s += S.lossW[w];
      atomicAdd(lossP + (size_t)qi * 64 + (blockIdx.x & 63), s);
    }
  }

  // epilogue: out_q = fl(x - resid_final)
  {
    const float* xp = x + (size_t)(rowBase + r8) * DIMD + c0;
    float* op = out_q + (size_t)(rowBase + r8) * DIMD + c0;
    #pragma unroll
    for (int h = 0; h < 8; ++h) {
      const float4 a = *(const float4*)(xp + h * 4);
      const float4 b = *(const float4*)&S.residF[r8][c0 + h * 4];
      *(float4*)(op + h * 4) =
          make_float4(__fsub_rn(a.x, b.x), __fsub_rn(a.y, b.y),
                      __fsub_rn(a.z, b.z), __fsub_rn(a.w, b.w));
    }
  }

  // folded k_loss: last block to finish sums lossP (device-scope atomics
  // both sides; __threadfence orders this block's lossP adds first).
  __syncthreads();
  if (tid == 0) {
    __threadfence();
    unsigned old = atomicAdd(doneCnt, 1u);
    S.cnt[0] = (old == (unsigned)(gridDim.x - 1)) ? 1 : 0;
  }
  __syncthreads();
  if (S.cnt[0] && tid < 64) {
    const int qi2 = tid >> 4;
    double s = 0.0;
    #pragma unroll
    for (int i = 0; i < 4; ++i)
      s += atomicAdd(lossP + (size_t)qi2 * 64 + (tid & 15) * 4 + i, 0.0);
    #pragma unroll
    for (int off = 8; off; off >>= 1) s += __shfl_down(s, off, 16);
    if ((tid & 15) == 0)
      out_loss[qi2] = (float)(s * (1.0 / (double)((size_t)MM * DIMD)));
  }
}

extern "C" void kernel_launch(void* const* d_in, const int* in_sizes, int n_in,
                              void* d_out, int out_size, void* d_ws, size_t ws_size,
                              hipStream_t stream) {
  const float* x = (const float*)d_in[0];        // [8,2048,256]
  const float* cb = (const float*)d_in[1];       // [4,1024,256]
  float* ws = (float*)d_ws;
  unsigned short* cb16 = (unsigned short*)ws;    // 1,048,576 ushort
  float* bK = ws + 524288;
  double* lossP = (double*)(ws + 528384);        // [QQ][64], byte off %8==0
  unsigned* done = (unsigned*)(ws + 528896);

  float* out = (float*)d_out;
  float* out_idx = out + (size_t)MM * DIMD;      // 4,194,304
  float* out_loss = out_idx + (size_t)QQ * MM;   // +65,536

  static bool attr_set = false;
  if (!attr_set) {
    hipFuncSetAttribute(reinterpret_cast<const void*>(k_fused),
                        hipFuncAttributeMaxDynamicSharedMemorySize,
                        (int)sizeof(SLds));
    attr_set = true;
  }

  k_prep<<<dim3(1024), dim3(256), 0, stream>>>(cb, cb16, bK, lossP, done);
  k_fused<<<dim3(MM / TM), dim3(512), sizeof(SLds), stream>>>(
      x, cb16, cb, bK, lossP, done, out, out_idx, out_loss);
}